// Round 8
// baseline (147.683 us; speedup 1.0000x reference)
//
#include <hip/hip_runtime.h>
#include <hip/hip_bf16.h>

#define BB 256
#define DD 512
#define CNUM 100000
#define CPAD 100096
#define NCHUNK 782          // CPAD / 128
#define NPART (NCHUNK * 2)

typedef __attribute__((ext_vector_type(8))) short bf16x8;
typedef __attribute__((ext_vector_type(4))) float f32x4;

__device__ __forceinline__ unsigned short f2bf(float f) {
  union { float f; unsigned int u; } v; v.f = f;
  unsigned int u = v.u;
  unsigned int r = u + 0x7FFFu + ((u >> 16) & 1u);
  return (unsigned short)(r >> 16);
}

// ---------------- Pass 0: normalize x rows -> bf16, per-sample margin trig ----
__global__ void k_prep_x(const float* __restrict__ x, const float* __restrict__ xnrm,
                         unsigned short* __restrict__ xn, float* __restrict__ cm,
                         float* __restrict__ sm) {
  int b = blockIdx.x;
  int lane = threadIdx.x;  // 64 threads
  const float4* xr = (const float4*)(x + (size_t)b * DD);
  float4 v0 = xr[lane * 2];
  float4 v1 = xr[lane * 2 + 1];
  float ss = v0.x * v0.x + v0.y * v0.y + v0.z * v0.z + v0.w * v0.w +
             v1.x * v1.x + v1.y * v1.y + v1.z * v1.z + v1.w * v1.w;
#pragma unroll
  for (int msk = 1; msk < 64; msk <<= 1) ss += __shfl_xor(ss, msk, 64);
  float inv = rsqrtf(ss);
  unsigned int p0 = (unsigned int)f2bf(v0.x * inv) | ((unsigned int)f2bf(v0.y * inv) << 16);
  unsigned int p1 = (unsigned int)f2bf(v0.z * inv) | ((unsigned int)f2bf(v0.w * inv) << 16);
  unsigned int p2 = (unsigned int)f2bf(v1.x * inv) | ((unsigned int)f2bf(v1.y * inv) << 16);
  unsigned int p3 = (unsigned int)f2bf(v1.z * inv) | ((unsigned int)f2bf(v1.w * inv) << 16);
  *(uint4*)(xn + (size_t)b * DD + lane * 8) = make_uint4(p0, p1, p2, p3);
  if (lane == 0) {
    float a = xnrm[b];
    float marg = 0.0035f * (a - 10.0f) + 0.45f;  // (U_M-L_M)/(U_A-L_A)
    cm[b] = cosf(marg);
    sm[b] = sinf(marg);
  }
}

// ---------------- Pass 1: fused W-normalize + cos GEMM + margin + LSE partials -
// R3 structure (plain __syncthreads, compiler-scheduled) with two changes:
//   * A-fragments read directly from L2-resident XN (no X LDS tile)
//   * W(kc+1) register loads issued AFTER barrier B -> full compute-phase cover
__global__ __launch_bounds__(512) void k_gemm(
    const unsigned short* __restrict__ xn, const float* __restrict__ w,
    const int* __restrict__ labels, const float* __restrict__ cmv,
    const float* __restrict__ smv, float2* __restrict__ part, float* __restrict__ tgt) {
  __shared__ short Ws[128 * 64];   // [col][k] bf16, XOR-swizzled, 16 KB
  __shared__ float sInvW[128];
  __shared__ int sLab[BB];
  __shared__ float sCm[BB], sSm[BB];

  int tid = threadIdx.x, wave = tid >> 6, lane = tid & 63;
  int wm = wave >> 1, wq = wave & 1;  // 4x2 waves: wave tile 64 rows x 64 cols
  int cbase = blockIdx.x * 128;

  if (tid < BB) {
    sLab[tid] = labels[tid];
    sCm[tid] = cmv[tid];
    sSm[tid] = smv[tid];
  }

  // W reg-staging: 4 threads per class row, 16 floats (4x f32x4) each.
  int wrow = tid >> 2, wseg = tid & 3;
  int wr_c = cbase + wrow;
  if (wr_c >= CNUM) wr_c = 0;  // safe addr; masked in epilogue
  const float* wptr = w + (size_t)wr_c * DD + wseg * 16;
  float ssacc = 0.0f;
  int wsw0 = wrow * 64 + ((wseg * 16) ^ ((wrow & 7) << 3));
  int wsw1 = wrow * 64 + ((wseg * 16 + 8) ^ ((wrow & 7) << 3));

  // A-fragment global base: row = wm*64 + m*16 + (lane&15), k-seg = (lane>>4)*8
  const unsigned short* xbase =
      xn + (size_t)(wm * 64 + (lane & 15)) * DD + (lane >> 4) * 8;

  f32x4 acc[4][4];
#pragma unroll
  for (int m = 0; m < 4; ++m)
#pragma unroll
    for (int n = 0; n < 4; ++n) acc[m][n] = (f32x4){0.f, 0.f, 0.f, 0.f};

  f32x4 wv[4];
#pragma unroll
  for (int j = 0; j < 4; ++j) wv[j] = *(const f32x4*)(wptr + j * 4);  // W(0)

  for (int kc = 0; kc < 8; ++kc) {
    const int k0 = kc * 64;
    __syncthreads();  // A: everyone done reading Ws(kc-1); drains W(kc) regs
    // pack W(kc): sum-of-squares + bf16 + swizzled LDS write
    {
      f32x4 a = wv[0], b = wv[1], c = wv[2], d = wv[3];
      ssacc += a[0]*a[0] + a[1]*a[1] + a[2]*a[2] + a[3]*a[3] +
               b[0]*b[0] + b[1]*b[1] + b[2]*b[2] + b[3]*b[3] +
               c[0]*c[0] + c[1]*c[1] + c[2]*c[2] + c[3]*c[3] +
               d[0]*d[0] + d[1]*d[1] + d[2]*d[2] + d[3]*d[3];
      unsigned int q0 = (unsigned int)f2bf(a[0]) | ((unsigned int)f2bf(a[1]) << 16);
      unsigned int q1 = (unsigned int)f2bf(a[2]) | ((unsigned int)f2bf(a[3]) << 16);
      unsigned int q2 = (unsigned int)f2bf(b[0]) | ((unsigned int)f2bf(b[1]) << 16);
      unsigned int q3 = (unsigned int)f2bf(b[2]) | ((unsigned int)f2bf(b[3]) << 16);
      unsigned int q4 = (unsigned int)f2bf(c[0]) | ((unsigned int)f2bf(c[1]) << 16);
      unsigned int q5 = (unsigned int)f2bf(c[2]) | ((unsigned int)f2bf(c[3]) << 16);
      unsigned int q6 = (unsigned int)f2bf(d[0]) | ((unsigned int)f2bf(d[1]) << 16);
      unsigned int q7 = (unsigned int)f2bf(d[2]) | ((unsigned int)f2bf(d[3]) << 16);
      *(uint4*)&Ws[wsw0] = make_uint4(q0, q1, q2, q3);
      *(uint4*)&Ws[wsw1] = make_uint4(q4, q5, q6, q7);
    }
    __syncthreads();  // B: Ws(kc) visible
    // issue W(kc+1) register loads -> covered by the whole compute phase below
    if (kc < 7) {
#pragma unroll
      for (int j = 0; j < 4; ++j) wv[j] = *(const f32x4*)(wptr + (kc + 1) * 64 + j * 4);
    }
    // compute tile kc: A-frags direct from global (L2-hot), B-frags from LDS
#pragma unroll
    for (int ks = 0; ks < 2; ++ks) {
      int krd = ks * 32 + (lane >> 4) * 8;
      int swz = (lane & 7) << 3;
      bf16x8 af[4], bfr[4];
#pragma unroll
      for (int m = 0; m < 4; ++m)
        af[m] = *(const bf16x8*)(xbase + (size_t)m * 16 * DD + k0 + ks * 32);
#pragma unroll
      for (int n = 0; n < 4; ++n) {
        int rb = wq * 64 + n * 16 + (lane & 15);
        bfr[n] = *(const bf16x8*)&Ws[rb * 64 + (krd ^ swz)];
      }
#pragma unroll
      for (int m = 0; m < 4; ++m)
#pragma unroll
        for (int n = 0; n < 4; ++n)
          acc[m][n] = __builtin_amdgcn_mfma_f32_16x16x32_bf16(af[m], bfr[n], acc[m][n], 0, 0, 0);
    }
  }

  // Per-row inverse norm: reduce ss over the 4 threads sharing a class row.
  ssacc += __shfl_xor(ssacc, 1, 64);
  ssacc += __shfl_xor(ssacc, 2, 64);
  __syncthreads();  // all waves past last compute before sInvW publish
  if (wseg == 0) sInvW[wrow] = rsqrtf(ssacc);
  __syncthreads();

  // Epilogue: cos = acc * invW, clamp, margin at label col, per-row (max, sum)
  // over this wave's 64 cols.  C/D layout: col = lane&15, row = (lane>>4)*4+reg.
  int g = lane >> 4, cb = lane & 15;
  float invc[4];
#pragma unroll
  for (int n = 0; n < 4; ++n) {
    int col = cbase + wq * 64 + n * 16 + cb;
    invc[n] = (col < CNUM) ? sInvW[wq * 64 + n * 16 + cb] : 0.0f;
  }
#pragma unroll
  for (int m = 0; m < 4; ++m) {
#pragma unroll
    for (int r = 0; r < 4; ++r) {
      int row = wm * 64 + m * 16 + g * 4 + r;
      int lab = sLab[row];
      float cmr = sCm[row], smr = sSm[row];
      float lg[4];
      float vmax = -1e30f;
#pragma unroll
      for (int n = 0; n < 4; ++n) {
        int col = cbase + wq * 64 + n * 16 + cb;
        float cv = acc[m][n][r] * invc[n];
        cv = fminf(1.0f, fmaxf(-1.0f, cv));
        float logit;
        if (col == lab) {
          float st = sqrtf(fmaxf(0.0f, 1.0f - cv * cv));
          float cm2 = cv * cmr - st * smr;
          logit = 64.0f * (cv > 0.0f ? cm2 : cv);
          tgt[row] = logit;  // exactly one (row, col==label) in the whole grid
        } else {
          logit = 64.0f * cv;
        }
        if (col >= CNUM) logit = -1e30f;
        lg[n] = logit;
        vmax = fmaxf(vmax, logit);
      }
#pragma unroll
      for (int msk = 1; msk < 16; msk <<= 1) vmax = fmaxf(vmax, __shfl_xor(vmax, msk, 64));
      float s = 0.0f;
#pragma unroll
      for (int n = 0; n < 4; ++n) s += __expf(lg[n] - vmax);
#pragma unroll
      for (int msk = 1; msk < 16; msk <<= 1) s += __shfl_xor(s, msk, 64);
      if (cb == 0) part[(size_t)row * NPART + blockIdx.x * 2 + wq] = make_float2(vmax, s);
    }
  }
}

// ---------------- Pass 2: per-row LSE merge over 1564 partials -> ce[b] -------
__global__ void k_merge(const float2* __restrict__ part, const float* __restrict__ tgt,
                        float* __restrict__ ce) {
  int b = blockIdx.x, t = threadIdx.x;
  float m = -1e30f, s = 0.0f;
  for (int i = t; i < NPART; i += 256) {
    float2 p = part[(size_t)b * NPART + i];
    float nm = fmaxf(m, p.x);
    s = s * __expf(m - nm) + p.y * __expf(p.x - nm);
    m = nm;
  }
  __shared__ float smx[256], ssm[256];
  smx[t] = m;
  ssm[t] = s;
  __syncthreads();
  for (int off = 128; off > 0; off >>= 1) {
    if (t < off) {
      float m2 = smx[t + off], s2 = ssm[t + off];
      float nm = fmaxf(smx[t], m2);
      ssm[t] = ssm[t] * __expf(smx[t] - nm) + s2 * __expf(m2 - nm);
      smx[t] = nm;
    }
    __syncthreads();
  }
  if (t == 0) ce[b] = smx[0] + logf(ssm[0]) - tgt[b];
}

// ---------------- Pass 3: final scalar ---------------------------------------
__global__ void k_final(const float* __restrict__ ce, const float* __restrict__ xnrm,
                        float* __restrict__ out) {
  int t = threadIdx.x;
  float cv = ce[t];
  float a = xnrm[t];
  float gv = a * (1.0f / (110.0f * 110.0f)) + 1.0f / a;
  __shared__ float s1[256], s2[256];
  s1[t] = cv;
  s2[t] = gv;
  __syncthreads();
  for (int off = 128; off > 0; off >>= 1) {
    if (t < off) {
      s1[t] += s1[t + off];
      s2[t] += s2[t + off];
    }
    __syncthreads();
  }
  if (t == 0) out[0] = s1[0] * (1.0f / 256.0f) + 35.0f * s2[0] * (1.0f / 256.0f);
}

extern "C" void kernel_launch(void* const* d_in, const int* in_sizes, int n_in,
                              void* d_out, int out_size, void* d_ws, size_t ws_size,
                              hipStream_t stream) {
  const float* x = (const float*)d_in[0];
  const float* xnrm = (const float*)d_in[1];
  const int* labels = (const int*)d_in[2];
  const float* w = (const float*)d_in[3];

  char* ws = (char*)d_ws;
  unsigned short* XN = (unsigned short*)ws;           // 256*512 bf16 = 256 KB
  size_t off = (size_t)BB * DD * 2;
  float* CM = (float*)(ws + off);  off += 1024;
  float* SM = (float*)(ws + off);  off += 1024;
  float* TGT = (float*)(ws + off); off += 1024;
  float* CE = (float*)(ws + off);  off += 1024;
  float2* PART = (float2*)(ws + off);  // 256 * 1564 * 8B = 3.2 MB

  k_prep_x<<<BB, 64, 0, stream>>>(x, xnrm, XN, CM, SM);
  k_gemm<<<NCHUNK, 512, 0, stream>>>(XN, w, labels, CM, SM, PART, TGT);
  k_merge<<<BB, 256, 0, stream>>>(PART, TGT, CE);
  k_final<<<1, 256, 0, stream>>>(CE, xnrm, (float*)d_out);
}

// Round 9
// 97.467 us; speedup vs baseline: 1.5152x; 1.5152x over previous
//
#include <hip/hip_runtime.h>
#include <hip/hip_bf16.h>

#define BB 256
#define DD 512
#define CNUM 100000
#define CPAD 100096
#define BN2 64
#define NCH 1564            // CPAD / 64
#define NPART NCH

typedef __attribute__((ext_vector_type(8))) short bf16x8;
typedef __attribute__((ext_vector_type(4))) float f32x4;

__device__ __forceinline__ unsigned short f2bf(float f) {
  union { float f; unsigned int u; } v; v.f = f;
  unsigned int u = v.u;
  unsigned int r = u + 0x7FFFu + ((u >> 16) & 1u);
  return (unsigned short)(r >> 16);
}

// ---------------- Pass 0: normalize x rows -> bf16 in MFMA-fragment layout ----
// XT[kchunk 0..15][row 0..255][32 elems]: a wave's A-fragment load is 64
// lanes x 16B contiguous (1KB).
__global__ void k_prep_x(const float* __restrict__ x, const float* __restrict__ xnrm,
                         unsigned short* __restrict__ xt, float* __restrict__ cm,
                         float* __restrict__ sm) {
  int b = blockIdx.x;
  int lane = threadIdx.x;  // 64 threads
  const float4* xr = (const float4*)(x + (size_t)b * DD);
  float4 v0 = xr[lane * 2];
  float4 v1 = xr[lane * 2 + 1];
  float ss = v0.x * v0.x + v0.y * v0.y + v0.z * v0.z + v0.w * v0.w +
             v1.x * v1.x + v1.y * v1.y + v1.z * v1.z + v1.w * v1.w;
#pragma unroll
  for (int msk = 1; msk < 64; msk <<= 1) ss += __shfl_xor(ss, msk, 64);
  float inv = rsqrtf(ss);
  unsigned int p0 = (unsigned int)f2bf(v0.x * inv) | ((unsigned int)f2bf(v0.y * inv) << 16);
  unsigned int p1 = (unsigned int)f2bf(v0.z * inv) | ((unsigned int)f2bf(v0.w * inv) << 16);
  unsigned int p2 = (unsigned int)f2bf(v1.x * inv) | ((unsigned int)f2bf(v1.y * inv) << 16);
  unsigned int p3 = (unsigned int)f2bf(v1.z * inv) | ((unsigned int)f2bf(v1.w * inv) << 16);
  // this thread holds elems k = lane*8 .. lane*8+7 -> kchunk = lane>>2, off = (lane&3)*8
  size_t idx = ((size_t)(lane >> 2) * BB + b) * 32 + (lane & 3) * 8;
  *(uint4*)(xt + idx) = make_uint4(p0, p1, p2, p3);
  if (lane == 0) {
    float a = xnrm[b];
    float marg = 0.0035f * (a - 10.0f) + 0.45f;  // (U_M-L_M)/(U_A-L_A)
    cm[b] = cosf(marg);
    sm[b] = sinf(marg);
  }
}

// ---------------- Pass 1: fused W-normalize + cos GEMM + margin + LSE partials -
// 256 thr / 4 waves; each wave owns 64 rows x all 64 block-cols.  A-frags come
// straight from L2-resident XT (contiguous); W is reg-staged fp32 one step
// ahead into double-buffered swizzled LDS.  ONE __syncthreads per K-step.
__global__ __launch_bounds__(256) void k_gemm(
    const unsigned short* __restrict__ xt, const float* __restrict__ w,
    const int* __restrict__ labels, const float* __restrict__ cmv,
    const float* __restrict__ smv, float2* __restrict__ part, float* __restrict__ tgt) {
  __shared__ short Ws[2][BN2 * 64];   // 8 KB per buffer, XOR-swizzled
  __shared__ float sInvW[BN2];
  __shared__ int sLab[BB];
  __shared__ float sCm[BB], sSm[BB];

  int tid = threadIdx.x, wave = tid >> 6, lane = tid & 63;
  int cbase = blockIdx.x * BN2;
  int cfrag = lane & 15, g = lane >> 4;

  sLab[tid] = labels[tid];
  sCm[tid] = cmv[tid];
  sSm[tid] = smv[tid];

  // W reg-staging: 4 threads per class row, 16 floats (4x f32x4) each.
  int wrow = tid >> 2, wseg = tid & 3;
  int wr_c = cbase + wrow;
  if (wr_c >= CNUM) wr_c = 0;  // safe addr; masked in epilogue
  const float* wptr = w + (size_t)wr_c * DD + wseg * 16;
  float ssacc = 0.0f;
  int wsw0 = wrow * 64 + ((wseg * 16) ^ ((wrow & 7) << 3));
  int wsw1 = wrow * 64 + ((wseg * 16 + 8) ^ ((wrow & 7) << 3));

  // A-fragment base: row = wave*64 + m*16 + cfrag, within-chunk byte g*8 elems
  const unsigned short* xb = xt + (size_t)(wave * 64 + cfrag) * 32 + g * 8;

  f32x4 acc[4][4];
#pragma unroll
  for (int m = 0; m < 4; ++m)
#pragma unroll
    for (int n = 0; n < 4; ++n) acc[m][n] = (f32x4){0.f, 0.f, 0.f, 0.f};

  f32x4 wv[4];

#define LOAD_W(T)                                                              \
  _Pragma("unroll") for (int j = 0; j < 4; ++j)                                \
      wv[j] = *(const f32x4*)(wptr + (T) * 64 + j * 4);

#define PACK_W(B)                                                              \
  {                                                                            \
    f32x4 a = wv[0], b = wv[1], c = wv[2], d = wv[3];                          \
    ssacc += a[0]*a[0] + a[1]*a[1] + a[2]*a[2] + a[3]*a[3] +                   \
             b[0]*b[0] + b[1]*b[1] + b[2]*b[2] + b[3]*b[3] +                   \
             c[0]*c[0] + c[1]*c[1] + c[2]*c[2] + c[3]*c[3] +                   \
             d[0]*d[0] + d[1]*d[1] + d[2]*d[2] + d[3]*d[3];                    \
    unsigned int q0 = (unsigned int)f2bf(a[0]) | ((unsigned int)f2bf(a[1]) << 16); \
    unsigned int q1 = (unsigned int)f2bf(a[2]) | ((unsigned int)f2bf(a[3]) << 16); \
    unsigned int q2 = (unsigned int)f2bf(b[0]) | ((unsigned int)f2bf(b[1]) << 16); \
    unsigned int q3 = (unsigned int)f2bf(b[2]) | ((unsigned int)f2bf(b[3]) << 16); \
    unsigned int q4 = (unsigned int)f2bf(c[0]) | ((unsigned int)f2bf(c[1]) << 16); \
    unsigned int q5 = (unsigned int)f2bf(c[2]) | ((unsigned int)f2bf(c[3]) << 16); \
    unsigned int q6 = (unsigned int)f2bf(d[0]) | ((unsigned int)f2bf(d[1]) << 16); \
    unsigned int q7 = (unsigned int)f2bf(d[2]) | ((unsigned int)f2bf(d[3]) << 16); \
    *(uint4*)&Ws[B][wsw0] = make_uint4(q0, q1, q2, q3);                        \
    *(uint4*)&Ws[B][wsw1] = make_uint4(q4, q5, q6, q7);                        \
  }

  // Prologue: stage W(0), leave W(1) in flight
  LOAD_W(0);
  PACK_W(0);          // compiler waits the loads here (one-time exposure)
  LOAD_W(1);
  __syncthreads();    // drains W(1) too (zero cover, once) + Ws[0] visible

#pragma unroll
  for (int kc = 0; kc < 8; ++kc) {
    const int p = kc & 1;
    // A-fragments for this step: 8 contiguous 1KB wave-loads from L2-hot XT
    bf16x8 af0[4], af1[4];
#pragma unroll
    for (int m = 0; m < 4; ++m) {
      af0[m] = *(const bf16x8*)(xb + ((size_t)(2 * kc) * BB + m * 16) * 32);
      af1[m] = *(const bf16x8*)(xb + ((size_t)(2 * kc + 1) * BB + m * 16) * 32);
    }
    // pack W(kc+1) into the alternate buffer (regs arrived; cover = prev step)
    if (kc < 7) {
      PACK_W(p ^ 1);
      if (kc < 6) LOAD_W(kc + 2);   // drains at this step's barrier (cover = compute)
    }
    // compute tile kc from Ws[p]
#pragma unroll
    for (int ks = 0; ks < 2; ++ks) {
      int krd = ks * 32 + g * 8;
      int swz = (lane & 7) << 3;
      bf16x8 bfr[4];
#pragma unroll
      for (int n = 0; n < 4; ++n) {
        int rb = n * 16 + cfrag;
        bfr[n] = *(const bf16x8*)&Ws[p][rb * 64 + (krd ^ swz)];
      }
#pragma unroll
      for (int m = 0; m < 4; ++m)
#pragma unroll
        for (int n = 0; n < 4; ++n)
          acc[m][n] = __builtin_amdgcn_mfma_f32_16x16x32_bf16(
              ks ? af1[m] : af0[m], bfr[n], acc[m][n], 0, 0, 0);
    }
    __syncthreads();  // Ws[p^1] visible; W(kc+2) regs drained (covered)
  }
#undef LOAD_W
#undef PACK_W

  // Per-row inverse norm: reduce ss over the 4 threads sharing a class row.
  ssacc += __shfl_xor(ssacc, 1, 64);
  ssacc += __shfl_xor(ssacc, 2, 64);
  if (wseg == 0) sInvW[wrow] = rsqrtf(ssacc);
  __syncthreads();

  // Epilogue: cos = acc * invW, clamp, margin at label col, per-row (max, sum)
  // over the block's 64 cols.  C/D layout: col = lane&15, row = (lane>>4)*4+reg.
  float invc[4];
#pragma unroll
  for (int n = 0; n < 4; ++n) {
    int col = cbase + n * 16 + cfrag;
    invc[n] = (col < CNUM) ? sInvW[n * 16 + cfrag] : 0.0f;
  }
#pragma unroll
  for (int m = 0; m < 4; ++m) {
#pragma unroll
    for (int r = 0; r < 4; ++r) {
      int row = wave * 64 + m * 16 + g * 4 + r;
      int lab = sLab[row];
      float cmr = sCm[row], smr = sSm[row];
      float lg[4];
      float vmax = -1e30f;
#pragma unroll
      for (int n = 0; n < 4; ++n) {
        int col = cbase + n * 16 + cfrag;
        float cv = acc[m][n][r] * invc[n];
        cv = fminf(1.0f, fmaxf(-1.0f, cv));
        float logit;
        if (col == lab) {
          float st = sqrtf(fmaxf(0.0f, 1.0f - cv * cv));
          float cm2 = cv * cmr - st * smr;
          logit = 64.0f * (cv > 0.0f ? cm2 : cv);
          tgt[row] = logit;  // exactly one (row, col==label) in the whole grid
        } else {
          logit = 64.0f * cv;
        }
        if (col >= CNUM) logit = -1e30f;
        lg[n] = logit;
        vmax = fmaxf(vmax, logit);
      }
#pragma unroll
      for (int msk = 1; msk < 16; msk <<= 1) vmax = fmaxf(vmax, __shfl_xor(vmax, msk, 64));
      float s = 0.0f;
#pragma unroll
      for (int n = 0; n < 4; ++n) s += __expf(lg[n] - vmax);
#pragma unroll
      for (int msk = 1; msk < 16; msk <<= 1) s += __shfl_xor(s, msk, 64);
      if (cfrag == 0) part[(size_t)row * NPART + blockIdx.x] = make_float2(vmax, s);
    }
  }
}

// ---------------- Pass 2: per-row LSE merge over 1564 partials -> ce[b] -------
__global__ void k_merge(const float2* __restrict__ part, const float* __restrict__ tgt,
                        float* __restrict__ ce) {
  int b = blockIdx.x, t = threadIdx.x;
  float m = -1e30f, s = 0.0f;
  for (int i = t; i < NPART; i += 256) {
    float2 p = part[(size_t)b * NPART + i];
    float nm = fmaxf(m, p.x);
    s = s * __expf(m - nm) + p.y * __expf(p.x - nm);
    m = nm;
  }
  __shared__ float smx[256], ssm[256];
  smx[t] = m;
  ssm[t] = s;
  __syncthreads();
  for (int off = 128; off > 0; off >>= 1) {
    if (t < off) {
      float m2 = smx[t + off], s2 = ssm[t + off];
      float nm = fmaxf(smx[t], m2);
      ssm[t] = ssm[t] * __expf(smx[t] - nm) + s2 * __expf(m2 - nm);
      smx[t] = nm;
    }
    __syncthreads();
  }
  if (t == 0) ce[b] = smx[0] + logf(ssm[0]) - tgt[b];
}

// ---------------- Pass 3: final scalar ---------------------------------------
__global__ void k_final(const float* __restrict__ ce, const float* __restrict__ xnrm,
                        float* __restrict__ out) {
  int t = threadIdx.x;
  float cv = ce[t];
  float a = xnrm[t];
  float gv = a * (1.0f / (110.0f * 110.0f)) + 1.0f / a;
  __shared__ float s1[256], s2[256];
  s1[t] = cv;
  s2[t] = gv;
  __syncthreads();
  for (int off = 128; off > 0; off >>= 1) {
    if (t < off) {
      s1[t] += s1[t + off];
      s2[t] += s2[t + off];
    }
    __syncthreads();
  }
  if (t == 0) out[0] = s1[0] * (1.0f / 256.0f) + 35.0f * s2[0] * (1.0f / 256.0f);
}

extern "C" void kernel_launch(void* const* d_in, const int* in_sizes, int n_in,
                              void* d_out, int out_size, void* d_ws, size_t ws_size,
                              hipStream_t stream) {
  const float* x = (const float*)d_in[0];
  const float* xnrm = (const float*)d_in[1];
  const int* labels = (const int*)d_in[2];
  const float* w = (const float*)d_in[3];

  char* ws = (char*)d_ws;
  unsigned short* XT = (unsigned short*)ws;           // 256*512 bf16 = 256 KB
  size_t off = (size_t)BB * DD * 2;
  float* CM = (float*)(ws + off);  off += 1024;
  float* SM = (float*)(ws + off);  off += 1024;
  float* TGT = (float*)(ws + off); off += 1024;
  float* CE = (float*)(ws + off);  off += 1024;
  float2* PART = (float2*)(ws + off);  // 256 * 1564 * 8B = 3.2 MB

  k_prep_x<<<BB, 64, 0, stream>>>(x, xnrm, XT, CM, SM);
  k_gemm<<<NCH, 256, 0, stream>>>(XT, w, labels, CM, SM, PART, TGT);
  k_merge<<<BB, 256, 0, stream>>>(PART, TGT, CE);
  k_final<<<1, 256, 0, stream>>>(CE, xnrm, (float*)d_out);
}